// Round 4
// baseline (486.158 us; speedup 1.0000x reference)
//
#include <hip/hip_runtime.h>

// VectorQuantizer on MI355X. d_out = FLOAT32 concat:
// [0]=vq_loss, [1]=commitment, [2..2+B)=idx(float), [2+B..)=quantized (B x 256).
// Round 4: touch-count reduction. 64 rows/wave (4 subtiles share B panel),
// contiguous epilogue mapping (it*16+pq*4), shuffle-aligned full-line stores,
// static per-group block partition (512 blocks = 2/CU), block-local i64 detect.

#define B_ROWS   131072
#define D_EMB    256
#define TPB      256
#define MAXT     8196
#define THETA    0.0625f

// ---- workspace layout (bytes) ----
#define WS_WSUM   0                        // 64 doubles (512B)
#define WS_GCNT   516                      // 4 ints
#define WS_GPOS   532                      // 4 ints
#define WS_GB     560                      // meta: 5 gb + 4 to + 4 tl = 13 ints
#define WS_CBH    1024                     // 512*256 bf16 hi (262144B)
#define WS_CBL    (WS_CBH + 262144)        // bf16 lo
#define WS_EN     (WS_CBL + 262144)        // 512 f32 norms
#define WS_ROWS   (WS_EN + 2048)           // 131072 ints
#define WS_TD     (WS_ROWS + 524288)       // MAXT ints
#define WS_NEED_NEW (WS_TD + 4 * MAXT)
#define WS_FLAGS  8

typedef __attribute__((ext_vector_type(8))) short bf16x8;
typedef __attribute__((ext_vector_type(4))) float f32x4;

__device__ __forceinline__ float bf2f(unsigned short u) {
    return __uint_as_float(((unsigned)u) << 16);
}

__device__ __forceinline__ void splitA(const float4& a0, const float4& a1,
                                       bf16x8& ah, bf16x8& al) {
    float ff[8] = {a0.x, a0.y, a0.z, a0.w, a1.x, a1.y, a1.z, a1.w};
    #pragma unroll
    for (int j = 0; j < 8; ++j) {
        unsigned u = __float_as_uint(ff[j]);
        ah[j] = (short)(u >> 16);
        float r = ff[j] - __uint_as_float(u & 0xffff0000u);
        al[j] = (short)(__float_as_uint(r) >> 16);
    }
}

// ============ prep: split codebook + norms (wave0) + group count (all) ============
__global__ void vq_prep2(const float* __restrict__ cbf, const int* __restrict__ nt,
                         unsigned short* __restrict__ cbh, unsigned short* __restrict__ cbl,
                         float* __restrict__ eN, int* __restrict__ gcnt) {
    __shared__ int sI64, c4[4];
    const int bid = blockIdx.x;      // 512
    const int tid = threadIdx.x;     // 256

    if (tid < 4) c4[tid] = 0;

    if (tid < 64) {                  // wave 0: split code=bid
        const int lane = tid;
        float4 v = *(const float4*)(cbf + bid * 256 + lane * 4);
        unsigned u0 = __float_as_uint(v.x), u1 = __float_as_uint(v.y);
        unsigned u2 = __float_as_uint(v.z), u3 = __float_as_uint(v.w);
        ushort4 h = make_ushort4((unsigned short)(u0 >> 16), (unsigned short)(u1 >> 16),
                                 (unsigned short)(u2 >> 16), (unsigned short)(u3 >> 16));
        float r0 = v.x - __uint_as_float(u0 & 0xffff0000u);
        float r1 = v.y - __uint_as_float(u1 & 0xffff0000u);
        float r2 = v.z - __uint_as_float(u2 & 0xffff0000u);
        float r3 = v.w - __uint_as_float(u3 & 0xffff0000u);
        ushort4 l = make_ushort4((unsigned short)(__float_as_uint(r0) >> 16),
                                 (unsigned short)(__float_as_uint(r1) >> 16),
                                 (unsigned short)(__float_as_uint(r2) >> 16),
                                 (unsigned short)(__float_as_uint(r3) >> 16));
        *(ushort4*)(cbh + bid * 256 + lane * 4) = h;
        *(ushort4*)(cbl + bid * 256 + lane * 4) = l;
        float s = fmaf(v.x, v.x, fmaf(v.y, v.y, fmaf(v.z, v.z, v.w * v.w)));
        #pragma unroll
        for (int d = 1; d < 64; d <<= 1) s += __shfl_xor(s, d);
        if (lane == 0) eN[bid] = s;
    } else if (tid < 128) {          // wave 1: local i64 detect (first 64 odd words)
        int o = (nt[2 * (tid - 64) + 1] != 0) ? 1 : 0;
        unsigned long long m = __ballot(o != 0);
        if (tid == 64) sI64 = (m == 0ULL) ? 1 : 0;
    }
    __syncthreads();

    const int i64 = sI64;
    const int row = bid * 256 + tid;
    const int tv  = i64 ? nt[2 * row] : nt[row];
    const int g   = (tv == 5) ? 0 : (tv == 6) ? 1 : (tv == 7) ? 2 : 3;
    atomicAdd(&c4[g], 1);
    __syncthreads();
    if (tid < 4) atomicAdd(&gcnt[tid], c4[tid]);
}

// ============ tiles (64-row) + block partition ============
__global__ void vq_tiles64(const int* __restrict__ gcnt, int* __restrict__ gpos,
                           int* __restrict__ meta, int* __restrict__ td) {
    __shared__ int off[4], cnt[4], to[4], tot;
    if (threadIdx.x == 0) {
        int o = 0, t = 0, tl[4], nb[4];
        for (int g = 0; g < 4; ++g) {
            cnt[g] = gcnt[g];
            off[g] = o; o += cnt[g];
            tl[g] = (cnt[g] + 63) >> 6;
            to[g] = t; t += tl[g];
            gpos[g] = off[g];
        }
        tot = t;
        int s3 = 0;
        for (int g = 0; g < 3; ++g) {
            nb[g] = (int)(512.0 * tl[g] / (double)(t > 0 ? t : 1) + 0.5);
            if (nb[g] < 1) nb[g] = 1;
            s3 += nb[g];
        }
        nb[3] = 512 - s3; if (nb[3] < 1) nb[3] = 1;
        meta[0] = 0;
        meta[1] = nb[0];
        meta[2] = nb[0] + nb[1];
        meta[3] = nb[0] + nb[1] + nb[2];
        meta[4] = meta[3] + nb[3];
        for (int g = 0; g < 4; ++g) { meta[5 + g] = to[g]; meta[9 + g] = tl[g]; }
    }
    __syncthreads();
    const int t = tot;
    for (int i = threadIdx.x; i < t; i += 64) {
        int g = 3;
        if (i < to[1]) g = 0; else if (i < to[2]) g = 1; else if (i < to[3]) g = 2;
        int b = i - to[g];
        int base = off[g] + b * 64;
        int nr = cnt[g] - b * 64; if (nr > 64) nr = 64;
        td[i] = nr | (base << 7) | (g << 24);
    }
}

// ============ scatter rows by group ============
__global__ void vq_bin2(const int* __restrict__ nt, int* __restrict__ gpos,
                        int* __restrict__ rows) {
    __shared__ int sI64, basev[4], pos[4];
    const int tid = threadIdx.x;
    if (tid < 4) pos[tid] = 0;
    if (tid >= 64 && tid < 128) {
        int o = (nt[2 * (tid - 64) + 1] != 0) ? 1 : 0;
        unsigned long long m = __ballot(o != 0);
        if (tid == 64) sI64 = (m == 0ULL) ? 1 : 0;
    }
    __syncthreads();
    const int i64 = sI64;
    const int row = blockIdx.x * 256 + tid;
    const int tv  = i64 ? nt[2 * row] : nt[row];
    const int g   = (tv == 5) ? 0 : (tv == 6) ? 1 : (tv == 7) ? 2 : 3;
    atomicAdd(&pos[g], 1);
    __syncthreads();
    if (tid < 4) { basev[tid] = atomicAdd(&gpos[tid], pos[tid]); pos[tid] = 0; }
    __syncthreads();
    int p = atomicAdd(&pos[g], 1);
    rows[basev[g] + p] = row;
}

// ============ scoring: one 64x128 tile per wave, 4 subtiles share B ============
__global__ __launch_bounds__(TPB, 2) void vq_score3(
    const float* __restrict__ zf,
    const float* __restrict__ cbf,
    const unsigned short* __restrict__ cbh,
    const unsigned short* __restrict__ cbl,
    const float* __restrict__ eN,
    const int* __restrict__ rows,
    const int* __restrict__ td,
    const int* __restrict__ meta,
    float* __restrict__ out,
    double* __restrict__ wsum)
{
    __shared__ int2   sT[4][16];
    __shared__ float2 sM[4][16];
    __shared__ float  sZZ[4][16];
    __shared__ double sRed[4];

    const int tid  = threadIdx.x;
    const int wave = tid >> 6;
    const int lane = tid & 63;
    const int col  = lane & 15;
    const int quad = lane >> 4;
    const int bid  = blockIdx.x;

    const int gb1 = meta[1], gb2 = meta[2], gb3 = meta[3];
    const int g = (bid < gb1) ? 0 : (bid < gb2) ? 1 : (bid < gb3) ? 2 : 3;
    const int gstart = meta[g];
    const int nbg    = meta[g + 1] - gstart;
    const int lb     = bid - gstart;
    const int to_g   = meta[5 + g];
    const int tl_g   = meta[9 + g];
    const int r0     = lb * 4 + wave;
    const int stride = nbg * 4;

    double lacc = 0.0;

    for (int t = r0; t < tl_g; t += stride) {
        const int d    = td[to_g + t];
        const int nr   = d & 127;
        const int base = (d >> 7) & 0x1FFFF;

        int nrs[4];
        #pragma unroll
        for (int st = 0; st < 4; ++st) {
            int n = nr - st * 16;
            nrs[st] = (n < 0) ? 0 : ((n > 16) ? 16 : n);
        }
        const float* za[4];
        #pragma unroll
        for (int st = 0; st < 4; ++st) {
            int nn = nrs[st];
            int ix = base + st * 16 + ((nn > 0) ? ((col < nn) ? col : (nn - 1)) : -st * 16);
            za[st] = zf + rows[ix] * 256 + quad * 8;
        }
        const unsigned short* bhp = cbh + (g * 128 + col) * 256 + quad * 8;
        const unsigned short* blp = cbl + (g * 128 + col) * 256 + quad * 8;

        f32x4 acc[4][8];
        #pragma unroll
        for (int st = 0; st < 4; ++st)
            #pragma unroll
            for (int t8 = 0; t8 < 8; ++t8) acc[st][t8] = (f32x4){0.f, 0.f, 0.f, 0.f};
        float zz[4] = {0.f, 0.f, 0.f, 0.f};

        #pragma unroll
        for (int c = 0; c < 8; ++c) {
            bf16x8 ah[4], al[4];
            #pragma unroll
            for (int st = 0; st < 4; ++st) {
                float4 x0 = *(const float4*)(za[st] + c * 32);
                float4 x1 = *(const float4*)(za[st] + c * 32 + 4);
                zz[st] = fmaf(x0.x,x0.x,fmaf(x0.y,x0.y,fmaf(x0.z,x0.z,fmaf(x0.w,x0.w,zz[st]))));
                zz[st] = fmaf(x1.x,x1.x,fmaf(x1.y,x1.y,fmaf(x1.z,x1.z,fmaf(x1.w,x1.w,zz[st]))));
                splitA(x0, x1, ah[st], al[st]);
            }
            #pragma unroll
            for (int t8 = 0; t8 < 8; ++t8) {
                bf16x8 bh = *(const bf16x8*)(bhp + t8 * 4096 + c * 32);
                bf16x8 bl = *(const bf16x8*)(blp + t8 * 4096 + c * 32);
                #pragma unroll
                for (int st = 0; st < 4; ++st) {
                    acc[st][t8] = __builtin_amdgcn_mfma_f32_16x16x32_bf16(ah[st], bh, acc[st][t8], 0, 0, 0);
                    acc[st][t8] = __builtin_amdgcn_mfma_f32_16x16x32_bf16(al[st], bh, acc[st][t8], 0, 0, 0);
                    acc[st][t8] = __builtin_amdgcn_mfma_f32_16x16x32_bf16(ah[st], bl, acc[st][t8], 0, 0, 0);
                }
            }
        }
        #pragma unroll
        for (int st = 0; st < 4; ++st) {
            zz[st] += __shfl_xor(zz[st], 16);
            zz[st] += __shfl_xor(zz[st], 32);
        }

        float e8[8];
        #pragma unroll
        for (int t8 = 0; t8 < 8; ++t8) e8[t8] = eN[g * 128 + t8 * 16 + col];

        #pragma unroll
        for (int st = 0; st < 4; ++st) {
            const int nrs_ = nrs[st];
            if (nrs_ <= 0) continue;
            if (quad == 0) sZZ[wave][col] = zz[st];

            // ---- per-row top-2 (score = ||e||^2 - 2 z.e); C row=quad*4+r ----
            #pragma unroll
            for (int r = 0; r < 4; ++r) {
                float m1 = __builtin_inff(), m2 = __builtin_inff();
                int   i1 = 0x7fffffff,      i2 = 0x7fffffff;
                #pragma unroll
                for (int t8 = 0; t8 < 8; ++t8) {
                    float sc = e8[t8] - 2.f * acc[st][t8][r];
                    int   ci = t8 * 16 + col;
                    if (sc < m1 || (sc == m1 && ci < i1)) { m2 = m1; i2 = i1; m1 = sc; i1 = ci; }
                    else if (sc < m2 || (sc == m2 && ci < i2)) { m2 = sc; i2 = ci; }
                }
                #pragma unroll
                for (int d2 = 1; d2 < 16; d2 <<= 1) {
                    float b1 = __shfl_xor(m1, d2);
                    int  bi1 = __shfl_xor(i1, d2);
                    float b2 = __shfl_xor(m2, d2);
                    int  bi2 = __shfl_xor(i2, d2);
                    if (b1 < m1 || (b1 == m1 && bi1 < i1)) {
                        float om = m1; int oi = i1;
                        m1 = b1; i1 = bi1;
                        if (b2 < om || (b2 == om && bi2 < oi)) { m2 = b2; i2 = bi2; }
                        else                                   { m2 = om; i2 = oi; }
                    } else {
                        if (b1 < m2 || (b1 == m2 && bi1 < i2)) { m2 = b1; i2 = bi1; }
                    }
                }
                if (col == 0) {
                    sT[wave][quad * 4 + r] = make_int2(i1, i2);
                    sM[wave][quad * 4 + r] = make_float2(m1, m2);
                }
            }

            // ---- gated epilogue (4 lanes per row, contiguous chunk mapping) ----
            const int s  = lane >> 2;
            const int pq = lane & 3;
            const bool valid = (s < nrs_);
            int grow = 0, c1 = 0, c2 = 0;
            float scm1 = 0.f, scm2 = 1e30f, zzr = 0.f;
            if (valid) {
                grow = rows[base + st * 16 + s];
                int2   tt = sT[wave][s];
                float2 mm = sM[wave][s];
                zzr = sZZ[wave][s];
                c1 = g * 128 + tt.x;
                c2 = g * 128 + tt.y;
                scm1 = mm.x; scm2 = mm.y;
            }
            int    wfin  = c1;
            double dfull = (double)(zzr + scm1);
            const bool need = valid && (scm2 - scm1 <= THETA);

            if (__any(need)) {     // rare: fp64 refine of close top-2
                double d1c = 0.0, d2c = 0.0;
                if (need) {
                    const float* zp = zf  + grow * 256;
                    const float* p1 = cbf + c1 * 256;
                    const float* p2 = cbf + c2 * 256;
                    #pragma unroll 4
                    for (int it = 0; it < 16; ++it) {
                        const int m = it * 16 + pq * 4;
                        float4 fz = *(const float4*)(zp + m);
                        float4 g1 = *(const float4*)(p1 + m);
                        float4 g2 = *(const float4*)(p2 + m);
                        double e;
                        e = (double)fz.x - (double)g1.x; d1c = fma(e, e, d1c);
                        e = (double)fz.y - (double)g1.y; d1c = fma(e, e, d1c);
                        e = (double)fz.z - (double)g1.z; d1c = fma(e, e, d1c);
                        e = (double)fz.w - (double)g1.w; d1c = fma(e, e, d1c);
                        e = (double)fz.x - (double)g2.x; d2c = fma(e, e, d2c);
                        e = (double)fz.y - (double)g2.y; d2c = fma(e, e, d2c);
                        e = (double)fz.z - (double)g2.z; d2c = fma(e, e, d2c);
                        e = (double)fz.w - (double)g2.w; d2c = fma(e, e, d2c);
                    }
                }
                double t1 = d1c + __shfl_xor(d1c, 1); t1 += __shfl_xor(t1, 2);
                double t2 = d2c + __shfl_xor(d2c, 1); t2 += __shfl_xor(t2, 2);
                if (need) {
                    bool take1 = (t1 < t2) || (t1 == t2 && c1 < c2);
                    wfin  = take1 ? c1 : c2;
                    dfull = take1 ? t1 : t2;
                }
            }

            // ---- winner copy: contiguous loads + shuffle-aligned stores ----
            {
                if (valid && pq == 0) lacc += dfull;
                const float* pw = cbf + wfin * 256;
                const int ob = 2 + B_ROWS + grow * 256;   // == 2 mod 4
                float4 cur = *(const float4*)(pw + pq * 4);
                #pragma unroll
                for (int it = 0; it < 16; ++it) {
                    float4 nxt = make_float4(0.f, 0.f, 0.f, 0.f);
                    if (it < 15) nxt = *(const float4*)(pw + (it + 1) * 16 + pq * 4);
                    float ax = __shfl(cur.x, lane + 1);
                    float ay = __shfl(cur.y, lane + 1);
                    float bx = __shfl(nxt.x, lane & 60);
                    float by = __shfl(nxt.y, lane & 60);
                    float nx = (pq < 3) ? ax : bx;
                    float ny = (pq < 3) ? ay : by;
                    const int q = it * 4 + pq;
                    if (valid) {
                        if (q == 0) *(float2*)(out + ob) = make_float2(cur.x, cur.y);
                        if (q < 63) *(float4*)(out + ob + 2 + 4 * q) = make_float4(cur.z, cur.w, nx, ny);
                        else        *(float2*)(out + ob + 254) = make_float2(cur.z, cur.w);
                    }
                    cur = nxt;
                }
                if (valid && pq == 0) out[2 + grow] = (float)wfin;
            }
        }
    }

    #pragma unroll
    for (int d2 = 1; d2 < 64; d2 <<= 1) lacc += __shfl_xor(lacc, d2);
    if (lane == 0) sRed[wave] = lacc;
    __syncthreads();
    if (tid == 0) atomicAdd(&wsum[blockIdx.x & 63], sRed[0] + sRed[1] + sRed[2] + sRed[3]);
}

// ===================== tiny-ws fallback (fp32 VALU path) =====================
__global__ void vq_detect(const unsigned short* cb, const int* nt, int* flag) {
    __shared__ int cnt, odd;
    if (threadIdx.x == 0) { cnt = 0; odd = 0; }
    __syncthreads();
    int c = 0, o = 0;
    for (int i = threadIdx.x; i < 512; i += 64) {
        unsigned short u = cb[2 * i];
        int e = (u >> 7) & 0xFF;
        if (e < 100 || e > 140) c++;
    }
    if (nt[2 * threadIdx.x + 1] != 0) o = 1;
    atomicAdd(&cnt, c);
    atomicAdd(&odd, o);
    __syncthreads();
    if (threadIdx.x == 0) {
        flag[0] = (cnt < 50) ? 1 : 0;
        flag[1] = (odd == 0) ? 1 : 0;
    }
}

__global__ __launch_bounds__(512, 2) void vq_main_f32(
    const int* __restrict__ nt,
    const float* __restrict__ zff,
    const float* __restrict__ cbf,
    float* __restrict__ out,
    double* __restrict__ wsum,
    const int* __restrict__ flag)
{
    if (flag[0] != 0) return;
    const int i64 = flag[1];

    __shared__ float  sE[256 * 132];
    __shared__ float  sZ[128 * 32];
    __shared__ int    sList[512];
    __shared__ int    sCnt[4], sPos[4];
    __shared__ int    sTop1[128], sTop2[128];
    __shared__ float  sEe[128];
    __shared__ double sRed[8];

    const int tid  = threadIdx.x;
    const int row0 = blockIdx.x * 512;

    if (tid < 4) { sCnt[tid] = 0; sPos[tid] = 0; }
    __syncthreads();
    {
        int t = i64 ? nt[2 * (row0 + tid)] : nt[row0 + tid];
        int g = (t == 5) ? 0 : (t == 6) ? 1 : (t == 7) ? 2 : 3;
        atomicAdd(&sCnt[g], 1);
        __syncthreads();
        int o1 = sCnt[0], o2 = o1 + sCnt[1], o3 = o2 + sCnt[2];
        int offg = (g == 0) ? 0 : (g == 1) ? o1 : (g == 2) ? o2 : o3;
        int p = atomicAdd(&sPos[g], 1);
        sList[offg + p] = row0 + tid;
    }
    __syncthreads();

    int cnt[4], off[4];
    cnt[0] = sCnt[0]; cnt[1] = sCnt[1]; cnt[2] = sCnt[2]; cnt[3] = sCnt[3];
    off[0] = 0; off[1] = cnt[0]; off[2] = off[1] + cnt[1]; off[3] = off[2] + cnt[2];

    const int ccol = tid & 31, rrow = tid >> 5;
    const int c0 = ccol * 4, rbase = rrow * 8;
    double lacc = 0.0;

    for (int gg = 0; gg < 4; ++gg) {
        const int n = cnt[gg];
        if (n == 0) continue;
        __syncthreads();
        for (int i = tid; i < 128 * 256; i += 512) {
            int c = i >> 8, k = i & 255;
            sE[k * 132 + c] = cbf[(gg * 128 + c) * 256 + k];
        }
        __syncthreads();
        if (tid < 128) {
            float s = 0.f;
            for (int k = 0; k < 256; ++k) { float v = sE[k * 132 + tid]; s = fmaf(v, v, s); }
            sEe[tid] = s;
        }
        __syncthreads();

        const int ntiles = (n + 127) >> 7;
        for (int tI = 0; tI < ntiles; ++tI) {
            const int tbase = off[gg] + tI * 128;
            const int nrows = min(128, n - tI * 128);
            float acc[8][4];
            #pragma unroll
            for (int r = 0; r < 8; ++r)
                #pragma unroll
                for (int q = 0; q < 4; ++q) acc[r][q] = 0.f;

            for (int kb = 0; kb < 8; ++kb) {
                __syncthreads();
                #pragma unroll
                for (int it = 0; it < 2; ++it) {
                    int i = it * 512 + tid;
                    int s = i >> 3, j = i & 7;
                    float4 v = make_float4(0.f, 0.f, 0.f, 0.f);
                    if (s < nrows) {
                        int gr = sList[tbase + s];
                        v = *(const float4*)(zff + gr * 256 + kb * 32 + j * 4);
                    }
                    *(float4*)&sZ[s * 32 + j * 4] = v;
                }
                __syncthreads();
                #pragma unroll
                for (int k4 = 0; k4 < 8; ++k4) {
                    const int kk = kb * 32 + k4 * 4;
                    const float4 e0 = *(const float4*)&sE[(kk + 0) * 132 + c0];
                    const float4 e1 = *(const float4*)&sE[(kk + 1) * 132 + c0];
                    const float4 e2 = *(const float4*)&sE[(kk + 2) * 132 + c0];
                    const float4 e3 = *(const float4*)&sE[(kk + 3) * 132 + c0];
                    #pragma unroll
                    for (int r = 0; r < 8; ++r) {
                        const float4 zv = *(const float4*)&sZ[(rbase + r) * 32 + k4 * 4];
                        acc[r][0] = fmaf(zv.x, e0.x, fmaf(zv.y, e1.x, fmaf(zv.z, e2.x, fmaf(zv.w, e3.x, acc[r][0]))));
                        acc[r][1] = fmaf(zv.x, e0.y, fmaf(zv.y, e1.y, fmaf(zv.z, e2.y, fmaf(zv.w, e3.y, acc[r][1]))));
                        acc[r][2] = fmaf(zv.x, e0.z, fmaf(zv.y, e1.z, fmaf(zv.z, e2.z, fmaf(zv.w, e3.z, acc[r][2]))));
                        acc[r][3] = fmaf(zv.x, e0.w, fmaf(zv.y, e1.w, fmaf(zv.z, e2.w, fmaf(zv.w, e3.w, acc[r][3]))));
                    }
                }
            }

            float eq[4] = { sEe[c0], sEe[c0 + 1], sEe[c0 + 2], sEe[c0 + 3] };
            for (int r = 0; r < 8; ++r) {
                float m1 = __builtin_inff(), m2 = __builtin_inff();
                int   i1 = 0x7fffffff,      i2 = 0x7fffffff;
                #pragma unroll
                for (int q = 0; q < 4; ++q) {
                    float sc = eq[q] - 2.f * acc[r][q];
                    int   ci = c0 + q;
                    if (sc < m1 || (sc == m1 && ci < i1)) { m2 = m1; i2 = i1; m1 = sc; i1 = ci; }
                    else if (sc < m2 || (sc == m2 && ci < i2)) { m2 = sc; i2 = ci; }
                }
                #pragma unroll
                for (int d = 1; d < 32; d <<= 1) {
                    float b1 = __shfl_xor(m1, d);
                    int  bi1 = __shfl_xor(i1, d);
                    float b2 = __shfl_xor(m2, d);
                    int  bi2 = __shfl_xor(i2, d);
                    if (b1 < m1 || (b1 == m1 && bi1 < i1)) {
                        float om = m1; int oi = i1;
                        m1 = b1; i1 = bi1;
                        if (b2 < om || (b2 == om && bi2 < oi)) { m2 = b2; i2 = bi2; }
                        else                                   { m2 = om; i2 = oi; }
                    } else {
                        if (b1 < m2 || (b1 == m2 && bi1 < i2)) { m2 = b1; i2 = bi1; }
                    }
                }
                if (ccol == 0) { sTop1[rbase + r] = i1; sTop2[rbase + r] = i2; }
            }
            __syncthreads();

            {
                const int s  = tid >> 2;
                const int pq = tid & 3;
                const bool valid = (s < nrows);
                double d1c = 0.0, d2c = 0.0;
                int gr = 0, c1g = 0, c2g = 0;
                if (valid) {
                    gr  = sList[tbase + s];
                    c1g = gg * 128 + sTop1[s];
                    c2g = gg * 128 + sTop2[s];
                    #pragma unroll 4
                    for (int it = 0; it < 16; ++it) {
                        float4 fz = *(const float4*)(zff + gr  * 256 + pq * 64 + it * 4);
                        float4 f1 = *(const float4*)(cbf + c1g * 256 + pq * 64 + it * 4);
                        float4 f2 = *(const float4*)(cbf + c2g * 256 + pq * 64 + it * 4);
                        double e;
                        e = (double)fz.x - (double)f1.x; d1c = fma(e, e, d1c);
                        e = (double)fz.y - (double)f1.y; d1c = fma(e, e, d1c);
                        e = (double)fz.z - (double)f1.z; d1c = fma(e, e, d1c);
                        e = (double)fz.w - (double)f1.w; d1c = fma(e, e, d1c);
                        e = (double)fz.x - (double)f2.x; d2c = fma(e, e, d2c);
                        e = (double)fz.y - (double)f2.y; d2c = fma(e, e, d2c);
                        e = (double)fz.z - (double)f2.z; d2c = fma(e, e, d2c);
                        e = (double)fz.w - (double)f2.w; d2c = fma(e, e, d2c);
                    }
                }
                double t1 = d1c + __shfl_xor(d1c, 1); t1 += __shfl_xor(t1, 2);
                double t2 = d2c + __shfl_xor(d2c, 1); t2 += __shfl_xor(t2, 2);
                if (valid) {
                    bool take1 = (t1 < t2) || (t1 == t2 && c1g < c2g);
                    int  w = take1 ? c1g : c2g;
                    lacc += take1 ? d1c : d2c;
                    const int obase = 2 + B_ROWS + gr * 256 + pq * 64;
                    #pragma unroll 4
                    for (int it = 0; it < 16; ++it) {
                        float4 f4 = *(const float4*)(cbf + w * 256 + pq * 64 + it * 4);
                        *(float2*)(out + obase + it * 4)     = make_float2(f4.x, f4.y);
                        *(float2*)(out + obase + it * 4 + 2) = make_float2(f4.z, f4.w);
                    }
                    if (pq == 0) out[2 + gr] = (float)w;
                }
            }
        }
    }

    #pragma unroll
    for (int d = 1; d < 64; d <<= 1) lacc += __shfl_xor(lacc, d);
    if ((tid & 63) == 0) sRed[tid >> 6] = lacc;
    __syncthreads();
    if (tid == 0) {
        double s = 0.0;
        #pragma unroll
        for (int i = 0; i < 8; ++i) s += sRed[i];
        atomicAdd(wsum, s);
    }
}

__global__ void vq_fin(const double* wsum, float* out, int n) {
    if (threadIdx.x == 0 && blockIdx.x == 0) {
        double m = 0.0;
        for (int i = 0; i < n; ++i) m += wsum[i];
        m /= ((double)B_ROWS * (double)D_EMB);
        out[0] = (float)m;
        out[1] = (float)(0.25 * m);
    }
}

extern "C" void kernel_launch(void* const* d_in, const int* in_sizes, int n_in,
                              void* d_out, int out_size, void* d_ws, size_t ws_size,
                              hipStream_t stream) {
    const int*   nt  = (const int*)d_in[0];
    const float* zf  = (const float*)d_in[1];
    const float* cbf = (const float*)d_in[2];
    float*  out  = (float*)d_out;
    double* wsum = (double*)((char*)d_ws + WS_WSUM);

    hipMemsetAsync(d_ws, 0, 1024, stream);

    if (ws_size >= (size_t)WS_NEED_NEW) {
        unsigned short* cbh  = (unsigned short*)((char*)d_ws + WS_CBH);
        unsigned short* cbl  = (unsigned short*)((char*)d_ws + WS_CBL);
        float* eN    = (float*)((char*)d_ws + WS_EN);
        int*   gcnt  = (int*)((char*)d_ws + WS_GCNT);
        int*   gpos  = (int*)((char*)d_ws + WS_GPOS);
        int*   metap = (int*)((char*)d_ws + WS_GB);
        int*   rowsp = (int*)((char*)d_ws + WS_ROWS);
        int*   tdp   = (int*)((char*)d_ws + WS_TD);
        vq_prep2<<<512, 256, 0, stream>>>(cbf, nt, cbh, cbl, eN, gcnt);
        vq_tiles64<<<1, 64, 0, stream>>>(gcnt, gpos, metap, tdp);
        vq_bin2<<<512, 256, 0, stream>>>(nt, gpos, rowsp);
        vq_score3<<<512, TPB, 0, stream>>>(zf, cbf, cbh, cbl, eN, rowsp, tdp, metap,
                                           out, wsum);
        vq_fin<<<1, 64, 0, stream>>>(wsum, out, 64);
    } else {
        int* flag = (int*)((char*)d_ws + WS_FLAGS);
        vq_detect<<<1, 64, 0, stream>>>((const unsigned short*)cbf, nt, flag);
        vq_main_f32<<<256, 512, 0, stream>>>(nt, zf, cbf, out, wsum, flag);
        vq_fin<<<1, 64, 0, stream>>>(wsum, out, 1);
    }
}